// Round 8
// baseline (4400.113 us; speedup 1.0000x reference)
//
#include <hip/hip_runtime.h>
#include <math.h>

#define NN 65536
#define KNB 16
#define THREADS 256
#define NBLOCKS (NN / THREADS)

// Packed-key exponent bias: keeps every live f64 key a NORMAL double
// (no subnormal flush hazard on v_min_f64/v_max_f64), order-preserving.
#define KEY_BIAS 0x00800000u

// ---------------------------------------------------------------------------
// Kernel 1: prep — s = x@Ws^T+bs, h = x@Wh^T+bh, candidate record (-2s, |s|^2)
// ---------------------------------------------------------------------------
__global__ __launch_bounds__(THREADS) void prep_kernel(
    const float* __restrict__ x,
    const float* __restrict__ Ws, const float* __restrict__ bs,
    const float* __restrict__ Wh, const float* __restrict__ bh,
    float4* __restrict__ cand, float* __restrict__ h)
{
    const int i = blockIdx.x * THREADS + threadIdx.x;
    const float4 xi = reinterpret_cast<const float4*>(x)[i];
    const float sx = fmaf(Ws[0], xi.x, fmaf(Ws[1], xi.y, fmaf(Ws[2],  xi.z, fmaf(Ws[3],  xi.w, bs[0]))));
    const float sy = fmaf(Ws[4], xi.x, fmaf(Ws[5], xi.y, fmaf(Ws[6],  xi.z, fmaf(Ws[7],  xi.w, bs[1]))));
    const float sz = fmaf(Ws[8], xi.x, fmaf(Ws[9], xi.y, fmaf(Ws[10], xi.z, fmaf(Ws[11], xi.w, bs[2]))));
    const float hh = fmaf(Wh[0], xi.x, fmaf(Wh[1], xi.y, fmaf(Wh[2],  xi.z, fmaf(Wh[3],  xi.w, bh[0]))));
    const float pn = fmaf(sx, sx, fmaf(sy, sy, sz * sz));
    cand[i] = make_float4(-2.0f * sx, -2.0f * sy, -2.0f * sz, pn);
    h[i] = hh;
}

// ---------------------------------------------------------------------------
// Kernel 2: brute-force kNN scan + fused GravNet epilogue.
// Rule-#20 fix (untested r6/r7, resubmitted): r5 showed VGPR_Count=44 — the
// lambda/array version put ALL state in scratch (each 8-cand block paid
// ~1270 cyc of scratch traffic). Everything is now NAMED registers via
// macros; identical arithmetic (r5 was bit-exact, absmax=0.0).
// ---------------------------------------------------------------------------
__global__ __launch_bounds__(THREADS, 1) void gravnet_kernel(
    const float* __restrict__ x,
    const float4* __restrict__ cand,
    const float* __restrict__ h,
    const float* __restrict__ Wout, const float* __restrict__ bout,
    float* __restrict__ partials)          // [NBLOCKS][64]
{
    const int i = blockIdx.x * THREADS + threadIdx.x;

    const float4 q = cand[i];          // (-2*s_i, |s_i|^2)
    const float six = -0.5f * q.x;     // s_i (bit-exact: *-2 then *-0.5)
    const float siy = -0.5f * q.y;
    const float siz = -0.5f * q.z;
    const float qn  = q.w;             // |s_i|^2

    // top-16 slots as NAMED f64 regs, ascending (d2,idx) packed order.
    // INIT: huge NORMAL double (exp=0x7FE), sorts after every real key.
    const double INIT = __longlong_as_double(0x7FE00000FFFFFFFFLL);
    double s0=INIT,s1=INIT,s2=INIT,s3=INIT,s4=INIT,s5=INIT,s6=INIT,s7=INIT,
           s8=INIT,s9=INIT,s10=INIT,s11=INIT,s12=INIT,s13=INIT,s14=INIT,s15=INIT;
    float thr = __uint_as_float(0x7FE00000u - KEY_BIAS);   // ~2.98e38

#define CE(sl) { const double lo_ = fmin(sl, run); run = fmax(sl, run); sl = lo_; }
#define UPPER8 CE(s8) CE(s9) CE(s10) CE(s11) CE(s12) CE(s13) CE(s14) CE(s15)
#define FULL16 CE(s0) CE(s1) CE(s2) CE(s3) CE(s4) CE(s5) CE(s6) CE(s7) \
               CE(s8) CE(s9) CE(s10) CE(s11) CE(s12) CE(s13) CE(s14) CE(s15)

#define INS(ddv, cidx)                                                        \
    if (__builtin_expect((ddv) < thr, 0)) {                                   \
        const float d2_ = (ddv) + qn;                                         \
        double run = __longlong_as_double((long long)(                        \
            ((unsigned long long)(__float_as_uint(d2_) + KEY_BIAS) << 32)     \
            | (unsigned)(cidx)));                                             \
        if (run > s7) { UPPER8 } else { FULL16 }                              \
        thr = __uint_as_float(                                                \
                  (unsigned)((unsigned long long)__double_as_longlong(s15)    \
                             >> 32) - KEY_BIAS) - qn;                         \
    }

#define DDOF(p) fmaf((p).x, six, fmaf((p).y, siy, fmaf((p).z, siz, (p).w)))

#define PROCESS(p0,p1,p2,p3,p4,p5,p6,p7, cbase) {                             \
    const float dd0=DDOF(p0), dd1=DDOF(p1), dd2=DDOF(p2), dd3=DDOF(p3);       \
    const float dd4=DDOF(p4), dd5=DDOF(p5), dd6=DDOF(p6), dd7=DDOF(p7);       \
    const float bmin_ = fminf(fminf(fminf(dd0,dd1),dd2),                      \
                        fminf(fminf(fminf(dd3,dd4),dd5), fminf(dd6,dd7)));    \
    if (__builtin_expect(bmin_ < thr, 0)) {                                   \
        INS(dd0,(cbase)+0) INS(dd1,(cbase)+1) INS(dd2,(cbase)+2)              \
        INS(dd3,(cbase)+3) INS(dd4,(cbase)+4) INS(dd5,(cbase)+5)              \
        INS(dd6,(cbase)+6) INS(dd7,(cbase)+7)                                 \
    } }

#define RELOAD(p0,p1,p2,p3,p4,p5,p6,p7, eb) {                                 \
    const float4* cp_ = cand + ((eb) & (NN - 1));                             \
    p0=cp_[0]; p1=cp_[1]; p2=cp_[2]; p3=cp_[3];                               \
    p4=cp_[4]; p5=cp_[5]; p6=cp_[6]; p7=cp_[7]; }

    // 4 rotating prefetch buffers, all named registers (32 float4 = 128 VGPR)
    float4 a0,a1,a2,a3,a4,a5,a6,a7;
    float4 b0,b1,b2,b3,b4,b5,b6,b7;
    float4 c0,c1,c2,c3,c4,c5,c6,c7;
    float4 d0,d1,d2,d3,d4,d5,d6,d7;
    RELOAD(a0,a1,a2,a3,a4,a5,a6,a7, 0)
    RELOAD(b0,b1,b2,b3,b4,b5,b6,b7, 8)
    RELOAD(c0,c1,c2,c3,c4,c5,c6,c7, 16)
    RELOAD(d0,d1,d2,d3,d4,d5,d6,d7, 24)

#pragma unroll 1
    for (int base = 0; base < NN; base += 32) {
        PROCESS(a0,a1,a2,a3,a4,a5,a6,a7, base)
        RELOAD (a0,a1,a2,a3,a4,a5,a6,a7, base + 32)
        PROCESS(b0,b1,b2,b3,b4,b5,b6,b7, base + 8)
        RELOAD (b0,b1,b2,b3,b4,b5,b6,b7, base + 40)
        PROCESS(c0,c1,c2,c3,c4,c5,c6,c7, base + 16)
        RELOAD (c0,c1,c2,c3,c4,c5,c6,c7, base + 48)
        PROCESS(d0,d1,d2,d3,d4,d5,d6,d7, base + 24)
        RELOAD (d0,d1,d2,d3,d4,d5,d6,d7, base + 56)
    }

    // Epilogue: exact d2 (reference's subtract-form rounding), weights, agg.
    // s0..s15 ascend in (d2,idx) == top_k return order -> same f32 sum order.
    float msum = 0.0f;
    float mmax = -INFINITY;
#define EPI(sl) {                                                             \
    const unsigned long long b_ = (unsigned long long)__double_as_longlong(sl);\
    const int idx_ = (int)(unsigned)(b_ & 0xFFFFFFFFu);                       \
    const float4 p_ = cand[idx_];                                             \
    const float dx_ = six - (-0.5f * p_.x);                                   \
    const float dy_ = siy - (-0.5f * p_.y);                                   \
    const float dz_ = siz - (-0.5f * p_.z);                                   \
    const float d2_ = fmaf(dx_, dx_, fmaf(dy_, dy_, dz_ * dz_));              \
    const float w_  = expf(-10.0f * d2_);                                     \
    const float m_  = h[idx_] * w_;                                           \
    msum += m_; mmax = fmaxf(mmax, m_); }
    EPI(s0) EPI(s1) EPI(s2) EPI(s3) EPI(s4) EPI(s5) EPI(s6) EPI(s7)
    EPI(s8) EPI(s9) EPI(s10) EPI(s11) EPI(s12) EPI(s13) EPI(s14) EPI(s15)

    const float mmean = msum * (1.0f / 16.0f);   // *2^-4 == /16 exactly

    // conv = [x_i, mean, max] @ Wout^T + bout ; elu ; block-level reduction
    const float4 xi = reinterpret_cast<const float4*>(x)[i];
    const float in0 = xi.x, in1 = xi.y, in2 = xi.z, in3 = xi.w;
    const float in4 = mmean, in5 = mmax;
    const int lane = threadIdx.x & 63;
    const int wid  = threadIdx.x >> 6;

    __shared__ float bsum[4][64];

    for (int o = 0; o < 64; ++o) {
        const float* wr = Wout + o * 6;
        float a = fmaf(wr[0], in0, fmaf(wr[1], in1, fmaf(wr[2], in2,
                  fmaf(wr[3], in3, fmaf(wr[4], in4, fmaf(wr[5], in5, bout[o]))))));
        a = (a > 0.0f) ? a : expm1f(a);
        a += __shfl_xor(a, 32);
        a += __shfl_xor(a, 16);
        a += __shfl_xor(a, 8);
        a += __shfl_xor(a, 4);
        a += __shfl_xor(a, 2);
        a += __shfl_xor(a, 1);
        if (lane == 0) bsum[wid][o] = a;
    }
    __syncthreads();
    if (threadIdx.x < 64) {
        const int o = threadIdx.x;
        partials[blockIdx.x * 64 + o] =
            (bsum[0][o] + bsum[1][o]) + (bsum[2][o] + bsum[3][o]);
    }
}

// ---------------------------------------------------------------------------
// Kernel 3: deterministic fixed-order reduction of block partials, then
// out = pooled @ Wfin^T + bfin.  (No atomics anywhere -> replay-stable.)
// ---------------------------------------------------------------------------
__global__ void final_kernel(const float* __restrict__ partials,  // [NBLOCKS][64]
                             const float* __restrict__ Wfin,
                             const float* __restrict__ bfin,
                             float* __restrict__ out)
{
    const int t = threadIdx.x;  // 64 threads, one channel each
    double acc = 0.0;
#pragma unroll 8
    for (int b = 0; b < NBLOCKS; ++b)
        acc += (double)partials[b * 64 + t];   // coalesced across lanes
    double v = acc * (double)Wfin[t];
    v += __shfl_xor(v, 32);
    v += __shfl_xor(v, 16);
    v += __shfl_xor(v, 8);
    v += __shfl_xor(v, 4);
    v += __shfl_xor(v, 2);
    v += __shfl_xor(v, 1);
    if (t == 0) out[0] = (float)(v + (double)bfin[0]);
}

extern "C" void kernel_launch(void* const* d_in, const int* in_sizes, int n_in,
                              void* d_out, int out_size, void* d_ws, size_t ws_size,
                              hipStream_t stream)
{
    const float* x    = (const float*)d_in[0];
    const float* Ws   = (const float*)d_in[1];
    const float* bs   = (const float*)d_in[2];
    const float* Wh   = (const float*)d_in[3];
    const float* bh   = (const float*)d_in[4];
    const float* Wout = (const float*)d_in[5];
    const float* bout = (const float*)d_in[6];
    const float* Wfin = (const float*)d_in[7];
    const float* bfin = (const float*)d_in[8];
    float* out = (float*)d_out;

    char* ws = (char*)d_ws;
    float4* cand     = (float4*)ws;                               // 1 MB
    float*  h        = (float*)(ws + (size_t)NN * 16);            // 256 KB
    float*  partials = (float*)(ws + (size_t)NN * 16 + (size_t)NN * 4);  // 64 KB

    prep_kernel<<<NBLOCKS, THREADS, 0, stream>>>(x, Ws, bs, Wh, bh, cand, h);
    gravnet_kernel<<<NBLOCKS, THREADS, 0, stream>>>(x, cand, h, Wout, bout, partials);
    final_kernel<<<1, 64, 0, stream>>>(partials, Wfin, bfin, out);
}

// Round 9
// 3721.174 us; speedup vs baseline: 1.1825x; 1.1825x over previous
//
#include <hip/hip_runtime.h>
#include <math.h>

#define NN 65536
#define KNB 16
#define THREADS 256
#define NBLOCKS (NN / THREADS)

// Packed-key exponent bias: keeps every live f64 key a NORMAL double
// (no subnormal flush hazard on f64 min/max), order-preserving.
#define KEY_BIAS 0x00800000u

// ---------------------------------------------------------------------------
// Kernel 1: prep — s = x@Ws^T+bs, h = x@Wh^T+bh, candidate record (-2s, |s|^2)
// ---------------------------------------------------------------------------
__global__ __launch_bounds__(THREADS) void prep_kernel(
    const float* __restrict__ x,
    const float* __restrict__ Ws, const float* __restrict__ bs,
    const float* __restrict__ Wh, const float* __restrict__ bh,
    float4* __restrict__ cand, float* __restrict__ h)
{
    const int i = blockIdx.x * THREADS + threadIdx.x;
    const float4 xi = reinterpret_cast<const float4*>(x)[i];
    const float sx = fmaf(Ws[0], xi.x, fmaf(Ws[1], xi.y, fmaf(Ws[2],  xi.z, fmaf(Ws[3],  xi.w, bs[0]))));
    const float sy = fmaf(Ws[4], xi.x, fmaf(Ws[5], xi.y, fmaf(Ws[6],  xi.z, fmaf(Ws[7],  xi.w, bs[1]))));
    const float sz = fmaf(Ws[8], xi.x, fmaf(Ws[9], xi.y, fmaf(Ws[10], xi.z, fmaf(Ws[11], xi.w, bs[2]))));
    const float hh = fmaf(Wh[0], xi.x, fmaf(Wh[1], xi.y, fmaf(Wh[2],  xi.z, fmaf(Wh[3],  xi.w, bh[0]))));
    const float pn = fmaf(sx, sx, fmaf(sy, sy, sz * sz));
    cand[i] = make_float4(-2.0f * sx, -2.0f * sy, -2.0f * sz, pn);
    h[i] = hh;
}

// ---------------------------------------------------------------------------
// Kernel 2: brute-force kNN scan + fused GravNet epilogue.
// ROUND-9 THEORY: r5/r8 identical at 4370us, VGPR=44 (= 32 slot VGPRs + ~12).
// ~32 VALU instr/candidate measured => compiler IF-CONVERTED the insertion
// chains (16-deep f64 cmp-exchange runs unconditionally per candidate as a
// select chain; __builtin_expect doesn't stop speculation of pure data
// movement). FIX: empty `asm volatile("")` in each guarded body — a
// side-effecting op cannot be speculated, forcing a real s_cbranch skip.
// Arithmetic is UNTOUCHED (r5/r8 were bit-exact, absmax=0.0).
// ---------------------------------------------------------------------------
__global__ __launch_bounds__(THREADS, 1) void gravnet_kernel(
    const float* __restrict__ x,
    const float4* __restrict__ cand,
    const float* __restrict__ h,
    const float* __restrict__ Wout, const float* __restrict__ bout,
    float* __restrict__ partials)          // [NBLOCKS][64]
{
    const int i = blockIdx.x * THREADS + threadIdx.x;

    const float4 q = cand[i];          // (-2*s_i, |s_i|^2)
    const float six = -0.5f * q.x;     // s_i (bit-exact: *-2 then *-0.5)
    const float siy = -0.5f * q.y;
    const float siz = -0.5f * q.z;
    const float qn  = q.w;             // |s_i|^2

    // top-16 slots as NAMED f64 regs, ascending (d2,idx) packed order.
    // INIT: huge NORMAL double (exp=0x7FE), sorts after every real key.
    const double INIT = __longlong_as_double(0x7FE00000FFFFFFFFLL);
    double s0=INIT,s1=INIT,s2=INIT,s3=INIT,s4=INIT,s5=INIT,s6=INIT,s7=INIT,
           s8=INIT,s9=INIT,s10=INIT,s11=INIT,s12=INIT,s13=INIT,s14=INIT,s15=INIT;
    float thr = __uint_as_float(0x7FE00000u - KEY_BIAS);   // ~2.98e38

#define CE(sl) { const double lo_ = fmin(sl, run); run = fmax(sl, run); sl = lo_; }
#define UPPER8 CE(s8) CE(s9) CE(s10) CE(s11) CE(s12) CE(s13) CE(s14) CE(s15)
#define FULL16 CE(s0) CE(s1) CE(s2) CE(s3) CE(s4) CE(s5) CE(s6) CE(s7) \
               CE(s8) CE(s9) CE(s10) CE(s11) CE(s12) CE(s13) CE(s14) CE(s15)

// NOTE: asm volatile("") = unspeculatable side effect -> REAL branch.
#define INS(ddv, cidx)                                                        \
    if (__builtin_expect((ddv) < thr, 0)) {                                   \
        asm volatile("");                                                     \
        const float d2_ = (ddv) + qn;                                         \
        double run = __longlong_as_double((long long)(                        \
            ((unsigned long long)(__float_as_uint(d2_) + KEY_BIAS) << 32)     \
            | (unsigned)(cidx)));                                             \
        if (run > s7) { UPPER8 } else { FULL16 }                              \
        thr = __uint_as_float(                                                \
                  (unsigned)((unsigned long long)__double_as_longlong(s15)    \
                             >> 32) - KEY_BIAS) - qn;                         \
    }

#define DDOF(p) fmaf((p).x, six, fmaf((p).y, siy, fmaf((p).z, siz, (p).w)))

#define PROCESS(p0,p1,p2,p3,p4,p5,p6,p7, cbase) {                             \
    const float dd0=DDOF(p0), dd1=DDOF(p1), dd2=DDOF(p2), dd3=DDOF(p3);       \
    const float dd4=DDOF(p4), dd5=DDOF(p5), dd6=DDOF(p6), dd7=DDOF(p7);       \
    const float bmin_ = fminf(fminf(fminf(dd0,dd1),dd2),                      \
                        fminf(fminf(fminf(dd3,dd4),dd5), fminf(dd6,dd7)));    \
    if (__builtin_expect(bmin_ < thr, 0)) {                                   \
        asm volatile("");                                                     \
        INS(dd0,(cbase)+0) INS(dd1,(cbase)+1) INS(dd2,(cbase)+2)              \
        INS(dd3,(cbase)+3) INS(dd4,(cbase)+4) INS(dd5,(cbase)+5)              \
        INS(dd6,(cbase)+6) INS(dd7,(cbase)+7)                                 \
    } }

#define RELOAD(p0,p1,p2,p3,p4,p5,p6,p7, eb) {                                 \
    const float4* cp_ = cand + ((eb) & (NN - 1));                             \
    p0=cp_[0]; p1=cp_[1]; p2=cp_[2]; p3=cp_[3];                               \
    p4=cp_[4]; p5=cp_[5]; p6=cp_[6]; p7=cp_[7]; }

    // 4 rotating prefetch buffers (compiler may sink loads; revisit with
    // counters once the branch fix is measured — one lever per round).
    float4 a0,a1,a2,a3,a4,a5,a6,a7;
    float4 b0,b1,b2,b3,b4,b5,b6,b7;
    float4 c0,c1,c2,c3,c4,c5,c6,c7;
    float4 d0,d1,d2,d3,d4,d5,d6,d7;
    RELOAD(a0,a1,a2,a3,a4,a5,a6,a7, 0)
    RELOAD(b0,b1,b2,b3,b4,b5,b6,b7, 8)
    RELOAD(c0,c1,c2,c3,c4,c5,c6,c7, 16)
    RELOAD(d0,d1,d2,d3,d4,d5,d6,d7, 24)

#pragma unroll 1
    for (int base = 0; base < NN; base += 32) {
        PROCESS(a0,a1,a2,a3,a4,a5,a6,a7, base)
        RELOAD (a0,a1,a2,a3,a4,a5,a6,a7, base + 32)
        PROCESS(b0,b1,b2,b3,b4,b5,b6,b7, base + 8)
        RELOAD (b0,b1,b2,b3,b4,b5,b6,b7, base + 40)
        PROCESS(c0,c1,c2,c3,c4,c5,c6,c7, base + 16)
        RELOAD (c0,c1,c2,c3,c4,c5,c6,c7, base + 48)
        PROCESS(d0,d1,d2,d3,d4,d5,d6,d7, base + 24)
        RELOAD (d0,d1,d2,d3,d4,d5,d6,d7, base + 56)
    }

    // Epilogue: exact d2 (reference's subtract-form rounding), weights, agg.
    // s0..s15 ascend in (d2,idx) == top_k return order -> same f32 sum order.
    float msum = 0.0f;
    float mmax = -INFINITY;
#define EPI(sl) {                                                             \
    const unsigned long long b_ = (unsigned long long)__double_as_longlong(sl);\
    const int idx_ = (int)(unsigned)(b_ & 0xFFFFFFFFu);                       \
    const float4 p_ = cand[idx_];                                             \
    const float dx_ = six - (-0.5f * p_.x);                                   \
    const float dy_ = siy - (-0.5f * p_.y);                                   \
    const float dz_ = siz - (-0.5f * p_.z);                                   \
    const float d2_ = fmaf(dx_, dx_, fmaf(dy_, dy_, dz_ * dz_));              \
    const float w_  = expf(-10.0f * d2_);                                     \
    const float m_  = h[idx_] * w_;                                           \
    msum += m_; mmax = fmaxf(mmax, m_); }
    EPI(s0) EPI(s1) EPI(s2) EPI(s3) EPI(s4) EPI(s5) EPI(s6) EPI(s7)
    EPI(s8) EPI(s9) EPI(s10) EPI(s11) EPI(s12) EPI(s13) EPI(s14) EPI(s15)

    const float mmean = msum * (1.0f / 16.0f);   // *2^-4 == /16 exactly

    // conv = [x_i, mean, max] @ Wout^T + bout ; elu ; block-level reduction
    const float4 xi = reinterpret_cast<const float4*>(x)[i];
    const float in0 = xi.x, in1 = xi.y, in2 = xi.z, in3 = xi.w;
    const float in4 = mmean, in5 = mmax;
    const int lane = threadIdx.x & 63;
    const int wid  = threadIdx.x >> 6;

    __shared__ float bsum[4][64];

    for (int o = 0; o < 64; ++o) {
        const float* wr = Wout + o * 6;
        float a = fmaf(wr[0], in0, fmaf(wr[1], in1, fmaf(wr[2], in2,
                  fmaf(wr[3], in3, fmaf(wr[4], in4, fmaf(wr[5], in5, bout[o]))))));
        a = (a > 0.0f) ? a : expm1f(a);
        a += __shfl_xor(a, 32);
        a += __shfl_xor(a, 16);
        a += __shfl_xor(a, 8);
        a += __shfl_xor(a, 4);
        a += __shfl_xor(a, 2);
        a += __shfl_xor(a, 1);
        if (lane == 0) bsum[wid][o] = a;
    }
    __syncthreads();
    if (threadIdx.x < 64) {
        const int o = threadIdx.x;
        partials[blockIdx.x * 64 + o] =
            (bsum[0][o] + bsum[1][o]) + (bsum[2][o] + bsum[3][o]);
    }
}

// ---------------------------------------------------------------------------
// Kernel 3: deterministic fixed-order reduction of block partials, then
// out = pooled @ Wfin^T + bfin.  (No atomics anywhere -> replay-stable.)
// ---------------------------------------------------------------------------
__global__ void final_kernel(const float* __restrict__ partials,  // [NBLOCKS][64]
                             const float* __restrict__ Wfin,
                             const float* __restrict__ bfin,
                             float* __restrict__ out)
{
    const int t = threadIdx.x;  // 64 threads, one channel each
    double acc = 0.0;
#pragma unroll 8
    for (int b = 0; b < NBLOCKS; ++b)
        acc += (double)partials[b * 64 + t];   // coalesced across lanes
    double v = acc * (double)Wfin[t];
    v += __shfl_xor(v, 32);
    v += __shfl_xor(v, 16);
    v += __shfl_xor(v, 8);
    v += __shfl_xor(v, 4);
    v += __shfl_xor(v, 2);
    v += __shfl_xor(v, 1);
    if (t == 0) out[0] = (float)(v + (double)bfin[0]);
}

extern "C" void kernel_launch(void* const* d_in, const int* in_sizes, int n_in,
                              void* d_out, int out_size, void* d_ws, size_t ws_size,
                              hipStream_t stream)
{
    const float* x    = (const float*)d_in[0];
    const float* Ws   = (const float*)d_in[1];
    const float* bs   = (const float*)d_in[2];
    const float* Wh   = (const float*)d_in[3];
    const float* bh   = (const float*)d_in[4];
    const float* Wout = (const float*)d_in[5];
    const float* bout = (const float*)d_in[6];
    const float* Wfin = (const float*)d_in[7];
    const float* bfin = (const float*)d_in[8];
    float* out = (float*)d_out;

    char* ws = (char*)d_ws;
    float4* cand     = (float4*)ws;                               // 1 MB
    float*  h        = (float*)(ws + (size_t)NN * 16);            // 256 KB
    float*  partials = (float*)(ws + (size_t)NN * 16 + (size_t)NN * 4);  // 64 KB

    prep_kernel<<<NBLOCKS, THREADS, 0, stream>>>(x, Ws, bs, Wh, bh, cand, h);
    gravnet_kernel<<<NBLOCKS, THREADS, 0, stream>>>(x, cand, h, Wout, bout, partials);
    final_kernel<<<1, 64, 0, stream>>>(partials, Wfin, bfin, out);
}

// Round 13
// 2123.768 us; speedup vs baseline: 2.0718x; 1.7522x over previous
//
#include <hip/hip_runtime.h>
#include <math.h>

#define NN 65536
#define KNB 16
#define THREADS 256
#define NBLOCKS (NN / THREADS)
#define TILE 2048                 // candidates per LDS tile (32 KB)

// Packed-key exponent bias: keeps every live f64 key a NORMAL double
// (no subnormal flush hazard on f64 min/max), order-preserving.
#define KEY_BIAS 0x00800000u

// ---------------------------------------------------------------------------
// Kernel 1: prep — s = x@Ws^T+bs, h = x@Wh^T+bh, candidate record (-2s, |s|^2)
// ---------------------------------------------------------------------------
__global__ __launch_bounds__(THREADS) void prep_kernel(
    const float* __restrict__ x,
    const float* __restrict__ Ws, const float* __restrict__ bs,
    const float* __restrict__ Wh, const float* __restrict__ bh,
    float4* __restrict__ cand, float* __restrict__ h)
{
    const int i = blockIdx.x * THREADS + threadIdx.x;
    const float4 xi = reinterpret_cast<const float4*>(x)[i];
    const float sx = fmaf(Ws[0], xi.x, fmaf(Ws[1], xi.y, fmaf(Ws[2],  xi.z, fmaf(Ws[3],  xi.w, bs[0]))));
    const float sy = fmaf(Ws[4], xi.x, fmaf(Ws[5], xi.y, fmaf(Ws[6],  xi.z, fmaf(Ws[7],  xi.w, bs[1]))));
    const float sz = fmaf(Ws[8], xi.x, fmaf(Ws[9], xi.y, fmaf(Ws[10], xi.z, fmaf(Ws[11], xi.w, bs[2]))));
    const float hh = fmaf(Wh[0], xi.x, fmaf(Wh[1], xi.y, fmaf(Wh[2],  xi.z, fmaf(Wh[3],  xi.w, bh[0]))));
    const float pn = fmaf(sx, sx, fmaf(sy, sy, sz * sz));
    cand[i] = make_float4(-2.0f * sx, -2.0f * sy, -2.0f * sz, pn);
    h[i] = hh;
}

// ---------------------------------------------------------------------------
// Kernel 2: brute-force kNN scan + fused GravNet epilogue.
// (Untested r10 restructure; resubmitted through r11/r12/r13 infra failures.)
// Two measured facts from r9 (dur 3721us, VALUBusy 45%, FETCH 8.5GB == full
// demand traffic):
//  (a) candidate loads serialize on L2 every 8-group  -> LDS tile staging:
//      each CU stages the 1MB table in 32KB tiles; scan reads are LDS
//      broadcast (uniform address) — near-free.
//  (b) inner insert chains were still if-converted (4M VALU cyc measured vs
//      0.9M lean model) -> wave-uniform `__any` ballot branches (scalar
//      branch, cannot be flattened) + INIT-pushthrough: non-inserting lanes
//      ripple INIT through the chain, a provable no-op (INIT >= all slots).
// Arithmetic identical to r5/r8/r9 (all bit-exact, absmax=0.0).
// ---------------------------------------------------------------------------
__global__ __launch_bounds__(THREADS, 1) void gravnet_kernel(
    const float* __restrict__ x,
    const float4* __restrict__ cand,
    const float* __restrict__ h,
    const float* __restrict__ Wout, const float* __restrict__ bout,
    float* __restrict__ partials)          // [NBLOCKS][64]
{
    const int i = blockIdx.x * THREADS + threadIdx.x;

    __shared__ float4 lds_cand[TILE];      // 32 KB tile of candidate records
    __shared__ float  bsum[4][64];

    const float4 q = cand[i];          // (-2*s_i, |s_i|^2)
    const float six = -0.5f * q.x;     // s_i (bit-exact: *-2 then *-0.5)
    const float siy = -0.5f * q.y;
    const float siz = -0.5f * q.z;
    const float qn  = q.w;             // |s_i|^2

    // top-16 slots as NAMED f64 regs, ascending (d2,idx) packed order.
    // INIT: huge NORMAL double (exp=0x7FE), sorts after every real key.
    const double INIT = __longlong_as_double(0x7FE00000FFFFFFFFLL);
    double s0=INIT,s1=INIT,s2=INIT,s3=INIT,s4=INIT,s5=INIT,s6=INIT,s7=INIT,
           s8=INIT,s9=INIT,s10=INIT,s11=INIT,s12=INIT,s13=INIT,s14=INIT,s15=INIT;
    float thr = __uint_as_float(0x7FE00000u - KEY_BIAS);   // ~2.98e38

#define CE(sl) { const double lo_ = fmin(sl, run); run = fmax(sl, run); sl = lo_; }
#define UPPER8 CE(s8) CE(s9) CE(s10) CE(s11) CE(s12) CE(s13) CE(s14) CE(s15)
#define FULL16 CE(s0) CE(s1) CE(s2) CE(s3) CE(s4) CE(s5) CE(s6) CE(s7) \
               CE(s8) CE(s9) CE(s10) CE(s11) CE(s12) CE(s13) CE(s14) CE(s15)

// Wave-uniform guard (scalar branch — not if-convertible). Lanes without a
// real insert push INIT through the chain: provably a no-op.
#define INS(ddv, cidx)                                                        \
    if (__any((ddv) < thr)) {                                                 \
        asm volatile("");                                                     \
        const float d2_ = (ddv) + qn;                                         \
        const unsigned long long ub_ =                                        \
            ((unsigned long long)(__float_as_uint(d2_) + KEY_BIAS) << 32)     \
            | (unsigned)(cidx);                                               \
        double run = ((ddv) < thr) ? __longlong_as_double((long long)ub_)     \
                                   : INIT;                                    \
        if (__all(run > s7)) { UPPER8 } else { FULL16 }                       \
        thr = __uint_as_float(                                                \
                  (unsigned)((unsigned long long)__double_as_longlong(s15)    \
                             >> 32) - KEY_BIAS) - qn;                         \
    }

#define DDOF(p) fmaf((p).x, six, fmaf((p).y, siy, fmaf((p).z, siz, (p).w)))

#define PROCESS(lb, cbase) {                                                  \
    const float4 p0_=lds_cand[(lb)+0], p1_=lds_cand[(lb)+1];                  \
    const float4 p2_=lds_cand[(lb)+2], p3_=lds_cand[(lb)+3];                  \
    const float4 p4_=lds_cand[(lb)+4], p5_=lds_cand[(lb)+5];                  \
    const float4 p6_=lds_cand[(lb)+6], p7_=lds_cand[(lb)+7];                  \
    const float dd0=DDOF(p0_), dd1=DDOF(p1_), dd2=DDOF(p2_), dd3=DDOF(p3_);   \
    const float dd4=DDOF(p4_), dd5=DDOF(p5_), dd6=DDOF(p6_), dd7=DDOF(p7_);   \
    const float bmin_ = fminf(fminf(fminf(dd0,dd1),dd2),                      \
                        fminf(fminf(fminf(dd3,dd4),dd5), fminf(dd6,dd7)));    \
    if (__any(bmin_ < thr)) {                                                 \
        asm volatile("");                                                     \
        INS(dd0,(cbase)+0) INS(dd1,(cbase)+1) INS(dd2,(cbase)+2)              \
        INS(dd3,(cbase)+3) INS(dd4,(cbase)+4) INS(dd5,(cbase)+5)              \
        INS(dd6,(cbase)+6) INS(dd7,(cbase)+7)                                 \
    } }

#pragma unroll 1
    for (int t = 0; t < NN; t += TILE) {
        __syncthreads();                       // previous tile fully consumed
#pragma unroll
        for (int k = 0; k < TILE / THREADS; ++k)   // coalesced 16B/lane
            lds_cand[threadIdx.x + k * THREADS] = cand[t + threadIdx.x + k * THREADS];
        __syncthreads();
#pragma unroll 2
        for (int lb = 0; lb < TILE; lb += 8) {
            PROCESS(lb, t + lb)
        }
    }

    // Epilogue: exact d2 (reference's subtract-form rounding), weights, agg.
    // s0..s15 ascend in (d2,idx) == top_k return order -> same f32 sum order.
    float msum = 0.0f;
    float mmax = -INFINITY;
#define EPI(sl) {                                                             \
    const unsigned long long b_ = (unsigned long long)__double_as_longlong(sl);\
    const int idx_ = (int)(unsigned)(b_ & 0xFFFFFFFFu);                       \
    const float4 p_ = cand[idx_];                                             \
    const float dx_ = six - (-0.5f * p_.x);                                   \
    const float dy_ = siy - (-0.5f * p_.y);                                   \
    const float dz_ = siz - (-0.5f * p_.z);                                   \
    const float d2_ = fmaf(dx_, dx_, fmaf(dy_, dy_, dz_ * dz_));              \
    const float w_  = expf(-10.0f * d2_);                                     \
    const float m_  = h[idx_] * w_;                                           \
    msum += m_; mmax = fmaxf(mmax, m_); }
    EPI(s0) EPI(s1) EPI(s2) EPI(s3) EPI(s4) EPI(s5) EPI(s6) EPI(s7)
    EPI(s8) EPI(s9) EPI(s10) EPI(s11) EPI(s12) EPI(s13) EPI(s14) EPI(s15)

    const float mmean = msum * (1.0f / 16.0f);   // *2^-4 == /16 exactly

    // conv = [x_i, mean, max] @ Wout^T + bout ; elu ; block-level reduction
    const float4 xi = reinterpret_cast<const float4*>(x)[i];
    const float in0 = xi.x, in1 = xi.y, in2 = xi.z, in3 = xi.w;
    const float in4 = mmean, in5 = mmax;
    const int lane = threadIdx.x & 63;
    const int wid  = threadIdx.x >> 6;

    for (int o = 0; o < 64; ++o) {
        const float* wr = Wout + o * 6;
        float a = fmaf(wr[0], in0, fmaf(wr[1], in1, fmaf(wr[2], in2,
                  fmaf(wr[3], in3, fmaf(wr[4], in4, fmaf(wr[5], in5, bout[o]))))));
        a = (a > 0.0f) ? a : expm1f(a);
        a += __shfl_xor(a, 32);
        a += __shfl_xor(a, 16);
        a += __shfl_xor(a, 8);
        a += __shfl_xor(a, 4);
        a += __shfl_xor(a, 2);
        a += __shfl_xor(a, 1);
        if (lane == 0) bsum[wid][o] = a;
    }
    __syncthreads();
    if (threadIdx.x < 64) {
        const int o = threadIdx.x;
        partials[blockIdx.x * 64 + o] =
            (bsum[0][o] + bsum[1][o]) + (bsum[2][o] + bsum[3][o]);
    }
}

// ---------------------------------------------------------------------------
// Kernel 3: deterministic fixed-order reduction of block partials, then
// out = pooled @ Wfin^T + bfin.  (No atomics anywhere -> replay-stable.)
// ---------------------------------------------------------------------------
__global__ void final_kernel(const float* __restrict__ partials,  // [NBLOCKS][64]
                             const float* __restrict__ Wfin,
                             const float* __restrict__ bfin,
                             float* __restrict__ out)
{
    const int t = threadIdx.x;  // 64 threads, one channel each
    double acc = 0.0;
#pragma unroll 8
    for (int b = 0; b < NBLOCKS; ++b)
        acc += (double)partials[b * 64 + t];   // coalesced across lanes
    double v = acc * (double)Wfin[t];
    v += __shfl_xor(v, 32);
    v += __shfl_xor(v, 16);
    v += __shfl_xor(v, 8);
    v += __shfl_xor(v, 4);
    v += __shfl_xor(v, 2);
    v += __shfl_xor(v, 1);
    if (t == 0) out[0] = (float)(v + (double)bfin[0]);
}

extern "C" void kernel_launch(void* const* d_in, const int* in_sizes, int n_in,
                              void* d_out, int out_size, void* d_ws, size_t ws_size,
                              hipStream_t stream)
{
    const float* x    = (const float*)d_in[0];
    const float* Ws   = (const float*)d_in[1];
    const float* bs   = (const float*)d_in[2];
    const float* Wh   = (const float*)d_in[3];
    const float* bh   = (const float*)d_in[4];
    const float* Wout = (const float*)d_in[5];
    const float* bout = (const float*)d_in[6];
    const float* Wfin = (const float*)d_in[7];
    const float* bfin = (const float*)d_in[8];
    float* out = (float*)d_out;

    char* ws = (char*)d_ws;
    float4* cand     = (float4*)ws;                               // 1 MB
    float*  h        = (float*)(ws + (size_t)NN * 16);            // 256 KB
    float*  partials = (float*)(ws + (size_t)NN * 16 + (size_t)NN * 4);  // 64 KB

    prep_kernel<<<NBLOCKS, THREADS, 0, stream>>>(x, Ws, bs, Wh, bh, cand, h);
    gravnet_kernel<<<NBLOCKS, THREADS, 0, stream>>>(x, cand, h, Wout, bout, partials);
    final_kernel<<<1, 64, 0, stream>>>(partials, Wfin, bfin, out);
}